// Round 2
// baseline (436.601 us; speedup 1.0000x reference)
//
#include <hip/hip_runtime.h>
#include <hip/hip_bf16.h>

#define N_TOK 4096
#define HD    512     // H * 64
typedef short v8s __attribute__((ext_vector_type(8)));
typedef float v4f __attribute__((ext_vector_type(4)));
typedef unsigned short u16;

__device__ __forceinline__ float bf2f(u16 x) {
  union { unsigned int u; float f; } c; c.u = ((unsigned int)x) << 16; return c.f;
}
__device__ __forceinline__ u16 f2bf(float f) {
  union { float f; unsigned int u; } c; c.f = f;
  return (u16)((c.u + 0x7fffu + ((c.u >> 16) & 1u)) >> 16);
}

// ---------- dtype detector: flag=0 -> inputs are bf16, flag=1 -> inputs are fp32 ----------
// Reads even-indexed u16s of Q. bf16 data: genuine N(0,1) samples, ~all in range.
// fp32 data: even u16 = low mantissa bits = uniform random -> ~42% in range.
__global__ void detect_k(const u16* __restrict__ q, int* __restrict__ flag) {
  int l = threadIdx.x;  // 64 threads
  u16 e = q[2 * l];
  float x = bf2f(e);
  int ex = (e >> 7) & 0xFF;
  float ax = fabsf(x);
  bool ok = (ex != 0xFF) && (ax < 64.f) && (ax > 1e-30f);
  unsigned long long m = __ballot(ok);
  if (l == 0) *flag = (__popcll(m) >= 48) ? 0 : 1;
}

// ---------- normalize any input to canonical bf16 (4 elems/thread) ----------
__global__ __launch_bounds__(256) void convert_k(const void* __restrict__ src, u16* __restrict__ dst,
                                                 int n4, const int* __restrict__ flag) {
  int i = blockIdx.x * 256 + threadIdx.x;
  if (i >= n4) return;
  short4 o;
  if (*flag) {
    float4 f = ((const float4*)src)[i];
    o.x = (short)f2bf(f.x); o.y = (short)f2bf(f.y);
    o.z = (short)f2bf(f.z); o.w = (short)f2bf(f.w);
  } else {
    o = ((const short4*)src)[i];
  }
  ((short4*)dst)[i] = o;
}

// ---------- tiled bf16 transpose: out[C][R] = in[R][C], R,C multiples of 64 ----------
__global__ __launch_bounds__(256) void tr_bf16(const u16* __restrict__ in, u16* __restrict__ out,
                                               int R, int C) {
  __shared__ __align__(16) u16 tile[64][72];
  const int r0 = blockIdx.x * 64, c0 = blockIdx.y * 64;
  const int t = threadIdx.x;
#pragma unroll
  for (int rep = 0; rep < 2; ++rep) {
    int idx = (t + rep * 256) * 8;
    int r = idx >> 6, c = idx & 63;
    *(v8s*)&tile[r][c] = *(const v8s*)(in + (size_t)(r0 + r) * C + (c0 + c));
  }
  __syncthreads();
#pragma unroll
  for (int rep = 0; rep < 2; ++rep) {
    int idx = (t + rep * 256) * 8;
    int oc = idx >> 6, orr = idx & 63;
    u16 tmp[8];
#pragma unroll
    for (int j = 0; j < 8; ++j) tmp[j] = tile[orr + j][oc];
    *(v8s*)(out + (size_t)(c0 + oc) * R + (r0 + orr)) = *(v8s*)tmp;
  }
}

// ---------- C[M,NB] = A[M,K] @ Bt[NB,K]^T + bias ----------
// outflag==nullptr -> bf16 out; else *outflag selects fp32(1)/bf16(0) out.
__global__ __launch_bounds__(256) void gemm_bt(const u16* __restrict__ A, const u16* __restrict__ Bt,
                                               const u16* __restrict__ bias, void* __restrict__ C,
                                               const int* __restrict__ outflag,
                                               int M, int NB, int K) {
  __shared__ __align__(16) u16 As[64][72];
  __shared__ __align__(16) u16 Bs[64][72];
  const int i0 = blockIdx.x * 64, j0 = blockIdx.y * 64;
  const int t = threadIdx.x, w = t >> 6, l = t & 63, quad = l >> 4, l15 = l & 15;
  v4f acc[4] = {};
  for (int k0 = 0; k0 < K; k0 += 64) {
#pragma unroll
    for (int rep = 0; rep < 2; ++rep) {
      int idx = (t + rep * 256) * 8;
      int r = idx >> 6, c = idx & 63;
      *(v8s*)&As[r][c] = *(const v8s*)(A + (size_t)(i0 + r) * K + k0 + c);
      *(v8s*)&Bs[r][c] = *(const v8s*)(Bt + (size_t)(j0 + r) * K + k0 + c);
    }
    __syncthreads();
#pragma unroll
    for (int h = 0; h < 2; ++h) {
      v8s a = *(const v8s*)&As[w * 16 + l15][h * 32 + quad * 8];
#pragma unroll
      for (int cb = 0; cb < 4; ++cb) {
        v8s b = *(const v8s*)&Bs[cb * 16 + l15][h * 32 + quad * 8];
        acc[cb] = __builtin_amdgcn_mfma_f32_16x16x32_bf16(a, b, acc[cb], 0, 0, 0);
      }
    }
    __syncthreads();
  }
  bool f32o = (outflag != nullptr) && (*outflag != 0);
#pragma unroll
  for (int cb = 0; cb < 4; ++cb) {
    int col = j0 + cb * 16 + l15;
    float bv = bf2f(bias[col]);
#pragma unroll
    for (int r = 0; r < 4; ++r) {
      int row = i0 + w * 16 + quad * 4 + r;
      float v = acc[cb][r] + bv;
      size_t idx = (size_t)row * NB + col;
      if (f32o) ((float*)C)[idx] = v;
      else      ((u16*)C)[idx] = f2bf(v);
    }
  }
}

// ---------- fused attention: one block = 64 q-rows x 1 head ----------
// qb,kb: [N, HD] bf16; vtb: [HD, N] bf16 (v transposed); adj: [N,N] bf16; ab: [N, HD] bf16
__global__ __launch_bounds__(256) void attn_kernel(const u16* __restrict__ qb, const u16* __restrict__ kb,
                                                   const u16* __restrict__ vtb, const u16* __restrict__ adj,
                                                   u16* __restrict__ ab) {
  __shared__ __align__(16) u16 Ks[64][72];
  __shared__ __align__(16) u16 Vs[64][72];      // Vs[e][m]
  __shared__ __align__(16) u16 Adjs[64][72];
  __shared__ __align__(16) u16 Ps[4][16][72];   // per-wave private P strip
  const int i0 = blockIdx.x * 64;
  const int h64 = blockIdx.y * 64;
  const int t = threadIdx.x, w = t >> 6, l = t & 63, quad = l >> 4, l15 = l & 15;
  const float scale = 0.125f;  // 1/sqrt(64)

  v8s qf[2];
#pragma unroll
  for (int h = 0; h < 2; ++h)
    qf[h] = *(const v8s*)(qb + (size_t)(i0 + w * 16 + l15) * HD + h64 + h * 32 + quad * 8);

  v4f oacc[4] = {};
  float lsum[4] = {0.f, 0.f, 0.f, 0.f};

  for (int m0 = 0; m0 < N_TOK; m0 += 64) {
#pragma unroll
    for (int rep = 0; rep < 2; ++rep) {
      int idx = (t + rep * 256) * 8;
      int r = idx >> 6, c = idx & 63;
      *(v8s*)&Ks[r][c]   = *(const v8s*)(kb  + (size_t)(m0 + r) * HD + h64 + c);
      *(v8s*)&Vs[r][c]   = *(const v8s*)(vtb + (size_t)(h64 + r) * N_TOK + m0 + c);
      *(v8s*)&Adjs[r][c] = *(const v8s*)(adj + (size_t)(i0 + r) * N_TOK + m0 + c);
    }
    __syncthreads();

    // S = q @ k^T  [16 x 64] per wave
    v4f s[4] = {};
#pragma unroll
    for (int h = 0; h < 2; ++h) {
#pragma unroll
      for (int cb = 0; cb < 4; ++cb) {
        v8s b = *(const v8s*)&Ks[cb * 16 + l15][h * 32 + quad * 8];
        s[cb] = __builtin_amdgcn_mfma_f32_16x16x32_bf16(qf[h], b, s[cb], 0, 0, 0);
      }
    }

    // p = exp(sigmoid(s/8) - 0.5 + 0.1*adj); bounded (0.6,1.8) -> no running max needed
#pragma unroll
    for (int cb = 0; cb < 4; ++cb) {
#pragma unroll
      for (int r = 0; r < 4; ++r) {
        float sv = s[cb][r] * scale;
        float sg = __builtin_amdgcn_rcpf(1.f + __expf(-sv));
        float ps = sg - 0.5f + 0.1f * bf2f(Adjs[w * 16 + quad * 4 + r][cb * 16 + l15]);
        float p = __expf(ps);
        lsum[r] += p;
        Ps[w][quad * 4 + r][cb * 16 + l15] = f2bf(p);
      }
    }
    // Ps is wave-private; enforce LDS write->read ordering explicitly.
    asm volatile("s_waitcnt lgkmcnt(0)" ::: "memory");

    // O += P @ v
#pragma unroll
    for (int h = 0; h < 2; ++h) {
      v8s pa = *(const v8s*)&Ps[w][l15][h * 32 + quad * 8];
#pragma unroll
      for (int eb = 0; eb < 4; ++eb) {
        v8s vb = *(const v8s*)&Vs[eb * 16 + l15][h * 32 + quad * 8];
        oacc[eb] = __builtin_amdgcn_mfma_f32_16x16x32_bf16(pa, vb, oacc[eb], 0, 0, 0);
      }
    }
    __syncthreads();
  }

  float rinv[4];
#pragma unroll
  for (int r = 0; r < 4; ++r) {
    float v = lsum[r];
    v += __shfl_xor(v, 1);
    v += __shfl_xor(v, 2);
    v += __shfl_xor(v, 4);
    v += __shfl_xor(v, 8);
    rinv[r] = __builtin_amdgcn_rcpf(v);
  }
#pragma unroll
  for (int eb = 0; eb < 4; ++eb) {
#pragma unroll
    for (int r = 0; r < 4; ++r) {
      int row = i0 + w * 16 + quad * 4 + r;
      ab[(size_t)row * HD + h64 + eb * 16 + l15] = f2bf(oacc[eb][r] * rinv[r]);
    }
  }
}

extern "C" void kernel_launch(void* const* d_in, const int* in_sizes, int n_in,
                              void* d_out, int out_size, void* d_ws, size_t ws_size,
                              hipStream_t stream) {
  (void)in_sizes; (void)n_in; (void)out_size; (void)ws_size;
  const void* Q   = d_in[0];
  const void* K   = d_in[1];
  const void* V   = d_in[2];
  const void* adj = d_in[3];
  const void* WQ  = d_in[4];
  const void* bQ  = d_in[5];
  const void* WK  = d_in[6];
  const void* bK  = d_in[7];
  const void* WV  = d_in[8];
  const void* bV  = d_in[9];
  const void* WO  = d_in[10];
  const void* bO  = d_in[11];

  char* p = (char*)d_ws;
  auto alloc = [&](size_t bytes) { char* r = p; p += (bytes + 255) & ~(size_t)255; return r; };
  int* flag  = (int*)alloc(4);
  u16* Qc    = (u16*)alloc((size_t)N_TOK * 512 * 2);
  u16* Kc    = (u16*)alloc((size_t)N_TOK * 512 * 2);
  u16* Vc    = (u16*)alloc((size_t)N_TOK * 512 * 2);
  u16* adjc  = (u16*)alloc((size_t)N_TOK * N_TOK * 2);
  u16* WQc   = (u16*)alloc((size_t)512 * 512 * 2);
  u16* WKc   = (u16*)alloc((size_t)512 * 512 * 2);
  u16* WVc   = (u16*)alloc((size_t)512 * 512 * 2);
  u16* WOc   = (u16*)alloc((size_t)512 * 64 * 2);
  u16* bQc   = (u16*)alloc(512 * 2);
  u16* bKc   = (u16*)alloc(512 * 2);
  u16* bVc   = (u16*)alloc(512 * 2);
  u16* bOc   = (u16*)alloc(64 * 2);
  u16* WQt   = (u16*)alloc((size_t)512 * 512 * 2);
  u16* WKt   = (u16*)alloc((size_t)512 * 512 * 2);
  u16* WVt   = (u16*)alloc((size_t)512 * 512 * 2);
  u16* WOt   = (u16*)alloc((size_t)64 * 512 * 2);
  u16* qb    = (u16*)alloc((size_t)N_TOK * HD * 2);
  u16* kb    = (u16*)alloc((size_t)N_TOK * HD * 2);
  u16* vb    = (u16*)alloc((size_t)N_TOK * HD * 2);
  u16* vtb   = (u16*)alloc((size_t)HD * N_TOK * 2);
  u16* ab    = (u16*)alloc((size_t)N_TOK * HD * 2);

  dim3 b256(256);
  detect_k<<<1, 64, 0, stream>>>((const u16*)Q, flag);

  auto conv = [&](const void* src, u16* dst, int n) {
    int n4 = n / 4;
    convert_k<<<(n4 + 255) / 256, b256, 0, stream>>>(src, dst, n4, flag);
  };
  conv(Q, Qc, N_TOK * 512);
  conv(K, Kc, N_TOK * 512);
  conv(V, Vc, N_TOK * 512);
  conv(adj, adjc, N_TOK * N_TOK);
  conv(WQ, WQc, 512 * 512);
  conv(WK, WKc, 512 * 512);
  conv(WV, WVc, 512 * 512);
  conv(WO, WOc, 512 * 64);
  conv(bQ, bQc, 512);
  conv(bK, bKc, 512);
  conv(bV, bVc, 512);
  conv(bO, bOc, 64);

  tr_bf16<<<dim3(8, 8), b256, 0, stream>>>(WQc, WQt, 512, 512);
  tr_bf16<<<dim3(8, 8), b256, 0, stream>>>(WKc, WKt, 512, 512);
  tr_bf16<<<dim3(8, 8), b256, 0, stream>>>(WVc, WVt, 512, 512);
  tr_bf16<<<dim3(8, 1), b256, 0, stream>>>(WOc, WOt, 512, 64);

  gemm_bt<<<dim3(64, 8), b256, 0, stream>>>(Qc, WQt, bQc, qb, nullptr, N_TOK, HD, 512);
  gemm_bt<<<dim3(64, 8), b256, 0, stream>>>(Kc, WKt, bKc, kb, nullptr, N_TOK, HD, 512);
  gemm_bt<<<dim3(64, 8), b256, 0, stream>>>(Vc, WVt, bVc, vb, nullptr, N_TOK, HD, 512);

  tr_bf16<<<dim3(64, 8), b256, 0, stream>>>(vb, vtb, N_TOK, HD);

  attn_kernel<<<dim3(N_TOK / 64, 8), b256, 0, stream>>>(qb, kb, vtb, adjc, ab);

  gemm_bt<<<dim3(64, 1), b256, 0, stream>>>(ab, WOt, bOc, (void*)d_out, flag, N_TOK, 64, 512);
}

// Round 3
// 300.396 us; speedup vs baseline: 1.4534x; 1.4534x over previous
//
#include <hip/hip_runtime.h>
#include <hip/hip_bf16.h>

#define N_TOK  4096
#define HD     512   // H * 64
#define NH     8
#define NSPLIT 4

typedef short v8s __attribute__((ext_vector_type(8)));
typedef float v4f __attribute__((ext_vector_type(4)));
typedef unsigned short u16;

#if __has_builtin(__builtin_amdgcn_exp2f)
#define USE_EXP2 1
#define ADJ_SCALE 0.14426950408889634f   // 0.1 * log2(e)
#else
#define USE_EXP2 0
#define ADJ_SCALE 0.1f
#endif

__device__ __forceinline__ float bf2f(u16 x) {
  union { unsigned int u; float f; } c; c.u = ((unsigned int)x) << 16; return c.f;
}
__device__ __forceinline__ u16 f2bf(float f) {
  union { float f; unsigned int u; } c; c.f = f;
  return (u16)((c.u + 0x7fffu + ((c.u >> 16) & 1u)) >> 16);
}

// ---------- dtype detector: flag=0 -> bf16 inputs, flag=1 -> fp32 inputs ----------
__global__ void detect_k(const u16* __restrict__ q, int* __restrict__ flag) {
  int l = threadIdx.x;  // 64 threads
  u16 e = q[2 * l];
  float x = bf2f(e);
  int ex = (e >> 7) & 0xFF;
  float ax = fabsf(x);
  bool ok = (ex != 0xFF) && (ax < 64.f) && (ax > 1e-30f);
  unsigned long long m = __ballot(ok);
  if (l == 0) *flag = (__popcll(m) >= 48) ? 0 : 1;
}

// ---------- batched Q/K/V normalize to bf16 ----------
__global__ __launch_bounds__(256) void conv_qkv_k(const void* __restrict__ s0, const void* __restrict__ s1,
                                                  const void* __restrict__ s2,
                                                  u16* __restrict__ d0, u16* __restrict__ d1,
                                                  u16* __restrict__ d2, const int* __restrict__ flag) {
  int z = blockIdx.y;
  const void* s = (z == 0) ? s0 : (z == 1) ? s1 : s2;
  u16* d = (z == 0) ? d0 : (z == 1) ? d1 : d2;
  int i = blockIdx.x * 256 + threadIdx.x;   // grid.x*256 == n/4 exactly
  short4 o;
  if (*flag) {
    float4 f = ((const float4*)s)[i];
    o.x = (short)f2bf(f.x); o.y = (short)f2bf(f.y);
    o.z = (short)f2bf(f.z); o.w = (short)f2bf(f.w);
  } else {
    o = ((const short4*)s)[i];
  }
  ((short4*)d)[i] = o;
}

// ---------- adj -> bf16 pre-scaled by ADJ_SCALE ----------
__global__ __launch_bounds__(256) void conv_adj_k(const void* __restrict__ src, u16* __restrict__ dst,
                                                  const int* __restrict__ flag) {
  int i = blockIdx.x * 256 + threadIdx.x;
  float4 f;
  if (*flag) {
    f = ((const float4*)src)[i];
  } else {
    short4 v = ((const short4*)src)[i];
    f.x = bf2f((u16)v.x); f.y = bf2f((u16)v.y); f.z = bf2f((u16)v.z); f.w = bf2f((u16)v.w);
  }
  short4 o;
  o.x = (short)f2bf(f.x * ADJ_SCALE); o.y = (short)f2bf(f.y * ADJ_SCALE);
  o.z = (short)f2bf(f.z * ADJ_SCALE); o.w = (short)f2bf(f.w * ADJ_SCALE);
  ((short4*)dst)[i] = o;
}

// ---------- all 4 biases in one launch ----------
__global__ void conv_bias_k(const void* sQ, const void* sK, const void* sV, const void* sO,
                            u16* dQ, u16* dK, u16* dV, u16* dO, const int* __restrict__ flag) {
  int i = blockIdx.x * 256 + threadIdx.x;
  const void* s; u16* d; int off;
  if (i < 512)       { s = sQ; d = dQ; off = i; }
  else if (i < 1024) { s = sK; d = dK; off = i - 512; }
  else if (i < 1536) { s = sV; d = dV; off = i - 1024; }
  else if (i < 1600) { s = sO; d = dO; off = i - 1536; }
  else return;
  float v = (*flag) ? ((const float*)s)[off] : bf2f(((const u16*)s)[off]);
  d[off] = f2bf(v);
}

// ---------- fused convert+transpose for all 4 weights: out[C][R] = bf16(in[R][C]) ----------
__global__ __launch_bounds__(256) void tr_w_k(const void* W0, const void* W1, const void* W2, const void* W3,
                                              u16* t0, u16* t1, u16* t2, u16* t3,
                                              const int* __restrict__ flag) {
  int z = blockIdx.z;
  const void* in; u16* out; int C;
  if (z == 0)      { in = W0; out = t0; C = 512; }
  else if (z == 1) { in = W1; out = t1; C = 512; }
  else if (z == 2) { in = W2; out = t2; C = 512; }
  else             { in = W3; out = t3; C = 64; if (blockIdx.y) return; }
  const int R = 512;
  __shared__ __align__(16) u16 tile[64][72];
  const int r0 = blockIdx.x * 64, c0 = blockIdx.y * 64;
  const int t = threadIdx.x;
  bool f32 = (*flag) != 0;
#pragma unroll
  for (int rep = 0; rep < 2; ++rep) {
    int idx = (t + rep * 256) * 8;
    int r = idx >> 6, c = idx & 63;
    if (f32) {
      const float* sp = (const float*)in + (size_t)(r0 + r) * C + (c0 + c);
      float4 a = *(const float4*)sp, b = *(const float4*)(sp + 4);
      u16 tmp[8] = { f2bf(a.x), f2bf(a.y), f2bf(a.z), f2bf(a.w),
                     f2bf(b.x), f2bf(b.y), f2bf(b.z), f2bf(b.w) };
      *(v8s*)&tile[r][c] = *(v8s*)tmp;
    } else {
      *(v8s*)&tile[r][c] = *(const v8s*)((const u16*)in + (size_t)(r0 + r) * C + (c0 + c));
    }
  }
  __syncthreads();
#pragma unroll
  for (int rep = 0; rep < 2; ++rep) {
    int idx = (t + rep * 256) * 8;
    int oc = idx >> 6, orr = idx & 63;
    u16 tmp[8];
#pragma unroll
    for (int j = 0; j < 8; ++j) tmp[j] = tile[orr + j][oc];
    *(v8s*)(out + (size_t)(c0 + oc) * R + (r0 + orr)) = *(v8s*)tmp;
  }
}

// ---------- plain bf16 transpose (for v -> v^T) ----------
__global__ __launch_bounds__(256) void tr_bf16(const u16* __restrict__ in, u16* __restrict__ out,
                                               int R, int C) {
  __shared__ __align__(16) u16 tile[64][72];
  const int r0 = blockIdx.x * 64, c0 = blockIdx.y * 64;
  const int t = threadIdx.x;
#pragma unroll
  for (int rep = 0; rep < 2; ++rep) {
    int idx = (t + rep * 256) * 8;
    int r = idx >> 6, c = idx & 63;
    *(v8s*)&tile[r][c] = *(const v8s*)(in + (size_t)(r0 + r) * C + (c0 + c));
  }
  __syncthreads();
#pragma unroll
  for (int rep = 0; rep < 2; ++rep) {
    int idx = (t + rep * 256) * 8;
    int oc = idx >> 6, orr = idx & 63;
    u16 tmp[8];
#pragma unroll
    for (int j = 0; j < 8; ++j) tmp[j] = tile[orr + j][oc];
    *(v8s*)(out + (size_t)(c0 + oc) * R + (r0 + orr)) = *(v8s*)tmp;
  }
}

// ---------- shared 64x64-tile GEMM body: C[.,NB] = A @ Bt^T + bias ----------
__device__ __forceinline__ void gemm_body(const u16* __restrict__ A, const u16* __restrict__ Bt,
                                          const u16* __restrict__ bias, void* __restrict__ C,
                                          bool f32o, int NB, int K) {
  __shared__ __align__(16) u16 As[64][72];
  __shared__ __align__(16) u16 Bs[64][72];
  const int i0 = blockIdx.x * 64, j0 = blockIdx.y * 64;
  const int t = threadIdx.x, w = t >> 6, l = t & 63, quad = l >> 4, l15 = l & 15;
  v4f acc[4] = {};
  for (int k0 = 0; k0 < K; k0 += 64) {
#pragma unroll
    for (int rep = 0; rep < 2; ++rep) {
      int idx = (t + rep * 256) * 8;
      int r = idx >> 6, c = idx & 63;
      *(v8s*)&As[r][c] = *(const v8s*)(A + (size_t)(i0 + r) * K + k0 + c);
      *(v8s*)&Bs[r][c] = *(const v8s*)(Bt + (size_t)(j0 + r) * K + k0 + c);
    }
    __syncthreads();
#pragma unroll
    for (int h = 0; h < 2; ++h) {
      v8s a = *(const v8s*)&As[w * 16 + l15][h * 32 + quad * 8];
#pragma unroll
      for (int cb = 0; cb < 4; ++cb) {
        v8s b = *(const v8s*)&Bs[cb * 16 + l15][h * 32 + quad * 8];
        acc[cb] = __builtin_amdgcn_mfma_f32_16x16x32_bf16(a, b, acc[cb], 0, 0, 0);
      }
    }
    __syncthreads();
  }
#pragma unroll
  for (int cb = 0; cb < 4; ++cb) {
    int col = j0 + cb * 16 + l15;
    float bv = bf2f(bias[col]);
#pragma unroll
    for (int r = 0; r < 4; ++r) {
      int row = blockIdx.x * 64 + w * 16 + quad * 4 + r;
      float v = acc[cb][r] + bv;
      size_t idx = (size_t)row * NB + col;
      if (f32o) ((float*)C)[idx] = v;
      else      ((u16*)C)[idx] = f2bf(v);
    }
  }
}

// ---------- batched Q/K/V projection GEMMs (blockIdx.z selects tensor) ----------
__global__ __launch_bounds__(256) void gemm_qkv_k(const u16* __restrict__ Ac0, const u16* __restrict__ Ac1,
                                                  const u16* __restrict__ Ac2,
                                                  const u16* __restrict__ t0, const u16* __restrict__ t1,
                                                  const u16* __restrict__ t2,
                                                  const u16* __restrict__ b0, const u16* __restrict__ b1,
                                                  const u16* __restrict__ b2,
                                                  u16* __restrict__ o0, u16* __restrict__ o1,
                                                  u16* __restrict__ o2) {
  int z = blockIdx.z;
  const u16* A  = (z == 0) ? Ac0 : (z == 1) ? Ac1 : Ac2;
  const u16* Bt = (z == 0) ? t0  : (z == 1) ? t1  : t2;
  const u16* bi = (z == 0) ? b0  : (z == 1) ? b1  : b2;
  u16* C        = (z == 0) ? o0  : (z == 1) ? o1  : o2;
  gemm_body(A, Bt, bi, C, false, HD, 512);
}

// ---------- final projection GEMM (runtime fp32/bf16 output) ----------
__global__ __launch_bounds__(256) void gemm_bt(const u16* __restrict__ A, const u16* __restrict__ Bt,
                                               const u16* __restrict__ bias, void* __restrict__ C,
                                               const int* __restrict__ outflag, int NB, int K) {
  gemm_body(A, Bt, bias, C, (*outflag) != 0, NB, K);
}

// ---------- fused attention, split over keys: block = (64 q-rows, head, split) ----------
__global__ __launch_bounds__(256) void attn_kernel(const u16* __restrict__ qb, const u16* __restrict__ kb,
                                                   const u16* __restrict__ vtb, const u16* __restrict__ adjc,
                                                   u16* __restrict__ Opart, float* __restrict__ Lpart) {
  __shared__ __align__(16) u16 Ks[64][72];
  __shared__ __align__(16) u16 Vs[64][72];      // Vs[e][m]
  __shared__ __align__(16) u16 Adjs[64][72];
  __shared__ __align__(16) u16 Ps[4][16][72];   // per-wave private
  const int i0 = blockIdx.x * 64;
  const int h64 = blockIdx.y * 64;
  const int z = blockIdx.z;
  const int m_begin = z * (N_TOK / NSPLIT);
  const int m_end = m_begin + (N_TOK / NSPLIT);
  const int t = threadIdx.x, w = t >> 6, l = t & 63, quad = l >> 4, l15 = l & 15;

  v8s qf[2];
#pragma unroll
  for (int h = 0; h < 2; ++h)
    qf[h] = *(const v8s*)(qb + (size_t)(i0 + w * 16 + l15) * HD + h64 + h * 32 + quad * 8);

  v4f oacc[4] = {};
  float lsum[4] = {0.f, 0.f, 0.f, 0.f};

  for (int m0 = m_begin; m0 < m_end; m0 += 64) {
#pragma unroll
    for (int rep = 0; rep < 2; ++rep) {
      int idx = (t + rep * 256) * 8;
      int r = idx >> 6, c = idx & 63;
      *(v8s*)&Ks[r][c]   = *(const v8s*)(kb   + (size_t)(m0 + r) * HD + h64 + c);
      *(v8s*)&Vs[r][c]   = *(const v8s*)(vtb  + (size_t)(h64 + r) * N_TOK + m0 + c);
      *(v8s*)&Adjs[r][c] = *(const v8s*)(adjc + (size_t)(i0 + r) * N_TOK + m0 + c);
    }
    __syncthreads();

    v4f s[4] = {};
#pragma unroll
    for (int h = 0; h < 2; ++h) {
#pragma unroll
      for (int cb = 0; cb < 4; ++cb) {
        v8s b = *(const v8s*)&Ks[cb * 16 + l15][h * 32 + quad * 8];
        s[cb] = __builtin_amdgcn_mfma_f32_16x16x32_bf16(qf[h], b, s[cb], 0, 0, 0);
      }
    }

#pragma unroll
    for (int cb = 0; cb < 4; ++cb) {
#pragma unroll
      for (int r = 0; r < 4; ++r) {
        float sraw = s[cb][r];
        float d = bf2f(Adjs[w * 16 + quad * 4 + r][cb * 16 + l15]);
#if USE_EXP2
        float u = __builtin_amdgcn_exp2f(sraw * -0.18033688f);           // e^(-s/8)
        float sig = __builtin_amdgcn_rcpf(1.f + u);
        float p = __builtin_amdgcn_exp2f(fmaf(sig, 1.44269504f, d - 0.72134752f));
#else
        float u = __expf(sraw * -0.125f);
        float sig = __builtin_amdgcn_rcpf(1.f + u);
        float p = __expf(sig + (d - 0.5f));
#endif
        lsum[r] += p;
        Ps[w][quad * 4 + r][cb * 16 + l15] = f2bf(p);
      }
    }
    asm volatile("s_waitcnt lgkmcnt(0)" ::: "memory");

#pragma unroll
    for (int h = 0; h < 2; ++h) {
      v8s pa = *(const v8s*)&Ps[w][l15][h * 32 + quad * 8];
#pragma unroll
      for (int eb = 0; eb < 4; ++eb) {
        v8s vb = *(const v8s*)&Vs[eb * 16 + l15][h * 32 + quad * 8];
        oacc[eb] = __builtin_amdgcn_mfma_f32_16x16x32_bf16(pa, vb, oacc[eb], 0, 0, 0);
      }
    }
    __syncthreads();
  }

#pragma unroll
  for (int r = 0; r < 4; ++r) {
    float v = lsum[r];
    v += __shfl_xor(v, 1);
    v += __shfl_xor(v, 2);
    v += __shfl_xor(v, 4);
    v += __shfl_xor(v, 8);
    lsum[r] = v;
  }
  if (l15 == 0) {
#pragma unroll
    for (int r = 0; r < 4; ++r)
      Lpart[((size_t)z * N_TOK + i0 + w * 16 + quad * 4 + r) * NH + blockIdx.y] = lsum[r];
  }
#pragma unroll
  for (int eb = 0; eb < 4; ++eb) {
#pragma unroll
    for (int r = 0; r < 4; ++r) {
      size_t row = (size_t)z * N_TOK + i0 + w * 16 + quad * 4 + r;
      Opart[row * HD + h64 + eb * 16 + l15] = f2bf(oacc[eb][r]);
    }
  }
}

// ---------- combine split partials: ab = (sum_s O_s) / (sum_s l_s) ----------
__global__ __launch_bounds__(256) void reduce_k(const u16* __restrict__ Opart, const float* __restrict__ Lpart,
                                                u16* __restrict__ ab) {
  int i = blockIdx.x * 256 + threadIdx.x;   // over N*HD/4
  int row = i >> 7;                          // HD/4 = 128
  int c4 = i & 127;
  int h = c4 >> 4;                           // (c4*4)/64
  float lv = 0.f;
#pragma unroll
  for (int s = 0; s < NSPLIT; ++s) lv += Lpart[((size_t)s * N_TOK + row) * NH + h];
  float ax = 0.f, ay = 0.f, az = 0.f, aw = 0.f;
#pragma unroll
  for (int s = 0; s < NSPLIT; ++s) {
    short4 v = ((const short4*)Opart)[(size_t)s * (N_TOK * HD / 4) + i];
    ax += bf2f((u16)v.x); ay += bf2f((u16)v.y); az += bf2f((u16)v.z); aw += bf2f((u16)v.w);
  }
  float rl = __builtin_amdgcn_rcpf(lv);
  short4 o;
  o.x = (short)f2bf(ax * rl); o.y = (short)f2bf(ay * rl);
  o.z = (short)f2bf(az * rl); o.w = (short)f2bf(aw * rl);
  ((short4*)ab)[i] = o;
}

extern "C" void kernel_launch(void* const* d_in, const int* in_sizes, int n_in,
                              void* d_out, int out_size, void* d_ws, size_t ws_size,
                              hipStream_t stream) {
  (void)in_sizes; (void)n_in; (void)out_size; (void)ws_size;
  const void* Q   = d_in[0];
  const void* K   = d_in[1];
  const void* V   = d_in[2];
  const void* adj = d_in[3];
  const void* WQ  = d_in[4];
  const void* bQ  = d_in[5];
  const void* WK  = d_in[6];
  const void* bK  = d_in[7];
  const void* WV  = d_in[8];
  const void* bV  = d_in[9];
  const void* WO  = d_in[10];
  const void* bO  = d_in[11];

  char* p = (char*)d_ws;
  auto alloc = [&](size_t bytes) { char* r = p; p += (bytes + 255) & ~(size_t)255; return r; };
  const size_t SZ = (size_t)N_TOK * HD * 2;  // 4.19 MB, 256-aligned

  int* flag  = (int*)alloc(256);
  u16* adjc  = (u16*)alloc((size_t)N_TOK * N_TOK * 2);
  // contiguous pool: Qc,Kc,Vc,vb — dead by attn time; Opart (NSPLIT*N*HD bf16) aliases it exactly
  u16* Qc    = (u16*)alloc(SZ);
  u16* Kc    = (u16*)alloc(SZ);
  u16* Vc    = (u16*)alloc(SZ);
  u16* vb    = (u16*)alloc(SZ);
  u16* Opart = Qc;                 // 4*SZ == NSPLIT*N_TOK*HD*2 exactly
  u16* qb    = (u16*)alloc(SZ);
  u16* kb    = (u16*)alloc(SZ);
  u16* vtb   = (u16*)alloc(SZ);
  u16* ab    = (u16*)alloc(SZ);
  u16* tQ    = (u16*)alloc((size_t)512 * 512 * 2);
  u16* tK    = (u16*)alloc((size_t)512 * 512 * 2);
  u16* tV    = (u16*)alloc((size_t)512 * 512 * 2);
  u16* tO    = (u16*)alloc((size_t)64 * 512 * 2);
  u16* bQc   = (u16*)alloc(512 * 2);
  u16* bKc   = (u16*)alloc(512 * 2);
  u16* bVc   = (u16*)alloc(512 * 2);
  u16* bOc   = (u16*)alloc(64 * 2);
  float* Lpart = (float*)alloc((size_t)NSPLIT * N_TOK * NH * 4);

  dim3 b256(256);
  detect_k<<<1, 64, 0, stream>>>((const u16*)Q, flag);

  conv_qkv_k<<<dim3(2048, 3), b256, 0, stream>>>(Q, K, V, Qc, Kc, Vc, flag);
  conv_adj_k<<<dim3(16384), b256, 0, stream>>>(adj, adjc, flag);
  conv_bias_k<<<dim3(7), b256, 0, stream>>>(bQ, bK, bV, bO, bQc, bKc, bVc, bOc, flag);
  tr_w_k<<<dim3(8, 8, 4), b256, 0, stream>>>(WQ, WK, WV, WO, tQ, tK, tV, tO, flag);

  gemm_qkv_k<<<dim3(64, 8, 3), b256, 0, stream>>>(Qc, Kc, Vc, tQ, tK, tV,
                                                  bQc, bKc, bVc, qb, kb, vb);

  tr_bf16<<<dim3(64, 8), b256, 0, stream>>>(vb, vtb, N_TOK, HD);

  attn_kernel<<<dim3(N_TOK / 64, NH, NSPLIT), b256, 0, stream>>>(qb, kb, vtb, adjc, Opart, Lpart);

  reduce_k<<<dim3(N_TOK * HD / 4 / 256), b256, 0, stream>>>(Opart, Lpart, ab);

  gemm_bt<<<dim3(64, 1), b256, 0, stream>>>(ab, tO, bOc, d_out, flag, 64, 512);
}

// Round 4
// 274.212 us; speedup vs baseline: 1.5922x; 1.0955x over previous
//
#include <hip/hip_runtime.h>
#include <hip/hip_bf16.h>

#define N_TOK  4096
#define HD     512   // H * 64
#define NH     8
#define NSPLIT 4

typedef short v8s __attribute__((ext_vector_type(8)));
typedef float v4f __attribute__((ext_vector_type(4)));
typedef unsigned short u16;

#define QSCALE   0.18033688011112042f   // log2(e)/8  (folded into q at projection)
#define ADJ2     0.14426950408889634f   // 0.1*log2(e) (folded into E=exp2(ADJ2*adj))
#define SIG2P    1.4426950408889634f    // log2(e)

__device__ __forceinline__ float bf2f(u16 x) {
  union { unsigned int u; float f; } c; c.u = ((unsigned int)x) << 16; return c.f;
}
__device__ __forceinline__ u16 f2bf(float f) {
  union { float f; unsigned int u; } c; c.f = f;
  return (u16)((c.u + 0x7fffu + ((c.u >> 16) & 1u)) >> 16);
}
__device__ __forceinline__ float fast_exp2(float x) {
#if __has_builtin(__builtin_amdgcn_exp2f)
  return __builtin_amdgcn_exp2f(x);
#else
  return exp2f(x);
#endif
}
__device__ __forceinline__ unsigned int pk_bf16(float a, float b) {
  union { __hip_bfloat162 h; unsigned int u; } c;
  c.h = __float22bfloat162_rn(make_float2(a, b));
  return c.u;
}

// ---------- dtype detector: flag=0 -> bf16 inputs, flag=1 -> fp32 inputs ----------
__global__ void detect_k(const u16* __restrict__ q, int* __restrict__ flag) {
  int l = threadIdx.x;  // 64 threads
  u16 e = q[2 * l];
  float x = bf2f(e);
  int ex = (e >> 7) & 0xFF;
  float ax = fabsf(x);
  bool ok = (ex != 0xFF) && (ax < 64.f) && (ax > 1e-30f);
  unsigned long long m = __ballot(ok);
  if (l == 0) *flag = (__popcll(m) >= 48) ? 0 : 1;
}

// ---------- adjE = exp2(ADJ2*adj) bf16; tail blocks convert the 4 biases ----------
__global__ __launch_bounds__(256) void conv_adjE_k(const void* __restrict__ adj, u16* __restrict__ adjE,
                                                   const void* sQ, const void* sK, const void* sV, const void* sO,
                                                   u16* dQ, u16* dK, u16* dV, u16* dO,
                                                   const int* __restrict__ flag) {
  int b = blockIdx.x;
  if (b >= 16384) {  // bias tail: 1600 scalars
    int i = (b - 16384) * 256 + threadIdx.x;
    const void* s; u16* d; int off;
    if (i < 512)       { s = sQ; d = dQ; off = i; }
    else if (i < 1024) { s = sK; d = dK; off = i - 512; }
    else if (i < 1536) { s = sV; d = dV; off = i - 1024; }
    else if (i < 1600) { s = sO; d = dO; off = i - 1536; }
    else return;
    float v = (*flag) ? ((const float*)s)[off] : bf2f(((const u16*)s)[off]);
    d[off] = f2bf(v);
    return;
  }
  int i = b * 256 + threadIdx.x;   // 4 elems/thread
  float4 f;
  if (*flag) {
    f = ((const float4*)adj)[i];
  } else {
    short4 v = ((const short4*)adj)[i];
    f.x = bf2f((u16)v.x); f.y = bf2f((u16)v.y); f.z = bf2f((u16)v.z); f.w = bf2f((u16)v.w);
  }
  unsigned int d0 = pk_bf16(fast_exp2(f.x * ADJ2), fast_exp2(f.y * ADJ2));
  unsigned int d1 = pk_bf16(fast_exp2(f.z * ADJ2), fast_exp2(f.w * ADJ2));
  ((uint2*)adjE)[i] = make_uint2(d0, d1);
}

// ---------- fused convert+transpose for all 4 weights: out[C][R] = bf16(in[R][C]) ----------
__global__ __launch_bounds__(256) void tr_w_k(const void* W0, const void* W1, const void* W2, const void* W3,
                                              u16* t0, u16* t1, u16* t2, u16* t3,
                                              const int* __restrict__ flag) {
  int z = blockIdx.z;
  const void* in; u16* out; int C;
  if (z == 0)      { in = W0; out = t0; C = 512; }
  else if (z == 1) { in = W1; out = t1; C = 512; }
  else if (z == 2) { in = W2; out = t2; C = 512; }
  else             { in = W3; out = t3; C = 64; if (blockIdx.y) return; }
  const int R = 512;
  __shared__ __align__(16) u16 tile[64][72];
  const int r0 = blockIdx.x * 64, c0 = blockIdx.y * 64;
  const int t = threadIdx.x;
  bool f32 = (*flag) != 0;
#pragma unroll
  for (int rep = 0; rep < 2; ++rep) {
    int idx = (t + rep * 256) * 8;
    int r = idx >> 6, c = idx & 63;
    if (f32) {
      const float* sp = (const float*)in + (size_t)(r0 + r) * C + (c0 + c);
      float4 a = *(const float4*)sp, b = *(const float4*)(sp + 4);
      uint4 q = make_uint4(pk_bf16(a.x, a.y), pk_bf16(a.z, a.w),
                           pk_bf16(b.x, b.y), pk_bf16(b.z, b.w));
      *(uint4*)&tile[r][c] = q;
    } else {
      *(v8s*)&tile[r][c] = *(const v8s*)((const u16*)in + (size_t)(r0 + r) * C + (c0 + c));
    }
  }
  __syncthreads();
#pragma unroll
  for (int rep = 0; rep < 2; ++rep) {
    int idx = (t + rep * 256) * 8;
    int oc = idx >> 6, orr = idx & 63;
    u16 tmp[8];
#pragma unroll
    for (int j = 0; j < 8; ++j) tmp[j] = tile[orr + j][oc];
    *(v8s*)(out + (size_t)(c0 + oc) * R + (r0 + orr)) = *(v8s*)tmp;
  }
}

// ---------- plain bf16 transpose (for v -> v^T) ----------
__global__ __launch_bounds__(256) void tr_bf16(const u16* __restrict__ in, u16* __restrict__ out,
                                               int R, int C) {
  __shared__ __align__(16) u16 tile[64][72];
  const int r0 = blockIdx.x * 64, c0 = blockIdx.y * 64;
  const int t = threadIdx.x;
#pragma unroll
  for (int rep = 0; rep < 2; ++rep) {
    int idx = (t + rep * 256) * 8;
    int r = idx >> 6, c = idx & 63;
    *(v8s*)&tile[r][c] = *(const v8s*)(in + (size_t)(r0 + r) * C + (c0 + c));
  }
  __syncthreads();
#pragma unroll
  for (int rep = 0; rep < 2; ++rep) {
    int idx = (t + rep * 256) * 8;
    int oc = idx >> 6, orr = idx & 63;
    u16 tmp[8];
#pragma unroll
    for (int j = 0; j < 8; ++j) tmp[j] = tile[orr + j][oc];
    *(v8s*)(out + (size_t)(c0 + oc) * R + (r0 + orr)) = *(v8s*)tmp;
  }
}

// ---------- batched Q/K/V projection GEMM with fused fp32->bf16 A conversion ----------
__global__ __launch_bounds__(256) void gemm_qkv_k(const void* A0, const void* A1, const void* A2,
                                                  const u16* __restrict__ t0, const u16* __restrict__ t1,
                                                  const u16* __restrict__ t2,
                                                  const u16* b0, const u16* b1, const u16* b2,
                                                  u16* o0, u16* o1, u16* o2,
                                                  const int* __restrict__ flag) {
  __shared__ __align__(16) u16 As[64][72];
  __shared__ __align__(16) u16 Bs[64][72];
  int z = blockIdx.z;
  const void* Araw = (z == 0) ? A0 : (z == 1) ? A1 : A2;
  const u16* Bt    = (z == 0) ? t0 : (z == 1) ? t1 : t2;
  const u16* bias  = (z == 0) ? b0 : (z == 1) ? b1 : b2;
  u16* C           = (z == 0) ? o0 : (z == 1) ? o1 : o2;
  const float oscale = (z == 0) ? QSCALE : 1.0f;   // fold score scale into q
  const bool f32 = (*flag) != 0;
  const int i0 = blockIdx.x * 64, j0 = blockIdx.y * 64;
  const int t = threadIdx.x, w = t >> 6, l = t & 63, quad = l >> 4, l15 = l & 15;
  v4f acc[4] = {};
  for (int k0 = 0; k0 < 512; k0 += 64) {
#pragma unroll
    for (int rep = 0; rep < 2; ++rep) {
      int idx = (t + rep * 256) * 8;
      int r = idx >> 6, c = idx & 63;
      if (f32) {
        const float* sp = (const float*)Araw + (size_t)(i0 + r) * 512 + k0 + c;
        float4 fa = *(const float4*)sp, fb = *(const float4*)(sp + 4);
        uint4 q = make_uint4(pk_bf16(fa.x, fa.y), pk_bf16(fa.z, fa.w),
                             pk_bf16(fb.x, fb.y), pk_bf16(fb.z, fb.w));
        *(uint4*)&As[r][c] = q;
      } else {
        *(v8s*)&As[r][c] = *(const v8s*)((const u16*)Araw + (size_t)(i0 + r) * 512 + k0 + c);
      }
      *(v8s*)&Bs[r][c] = *(const v8s*)(Bt + (size_t)(j0 + r) * 512 + k0 + c);
    }
    __syncthreads();
#pragma unroll
    for (int h = 0; h < 2; ++h) {
      v8s a = *(const v8s*)&As[w * 16 + l15][h * 32 + quad * 8];
#pragma unroll
      for (int cb = 0; cb < 4; ++cb) {
        v8s b = *(const v8s*)&Bs[cb * 16 + l15][h * 32 + quad * 8];
        acc[cb] = __builtin_amdgcn_mfma_f32_16x16x32_bf16(a, b, acc[cb], 0, 0, 0);
      }
    }
    __syncthreads();
  }
#pragma unroll
  for (int cb = 0; cb < 4; ++cb) {
    int col = j0 + cb * 16 + l15;
    float bv = bf2f(bias[col]);
#pragma unroll
    for (int r = 0; r < 4; ++r) {
      int row = i0 + w * 16 + quad * 4 + r;
      C[(size_t)row * HD + col] = f2bf((acc[cb][r] + bv) * oscale);
    }
  }
}

// ---------- final projection: C = ab @ tO^T + bias (runtime fp32/bf16 out) ----------
__global__ __launch_bounds__(256) void gemm_bt(const u16* __restrict__ A, const u16* __restrict__ Bt,
                                               const u16* __restrict__ bias, void* __restrict__ C,
                                               const int* __restrict__ outflag, int NB, int K) {
  __shared__ __align__(16) u16 As[64][72];
  __shared__ __align__(16) u16 Bs[64][72];
  const int i0 = blockIdx.x * 64, j0 = blockIdx.y * 64;
  const int t = threadIdx.x, w = t >> 6, l = t & 63, quad = l >> 4, l15 = l & 15;
  v4f acc[4] = {};
  for (int k0 = 0; k0 < K; k0 += 64) {
#pragma unroll
    for (int rep = 0; rep < 2; ++rep) {
      int idx = (t + rep * 256) * 8;
      int r = idx >> 6, c = idx & 63;
      *(v8s*)&As[r][c] = *(const v8s*)(A + (size_t)(i0 + r) * K + k0 + c);
      *(v8s*)&Bs[r][c] = *(const v8s*)(Bt + (size_t)(j0 + r) * K + k0 + c);
    }
    __syncthreads();
#pragma unroll
    for (int h = 0; h < 2; ++h) {
      v8s a = *(const v8s*)&As[w * 16 + l15][h * 32 + quad * 8];
#pragma unroll
      for (int cb = 0; cb < 4; ++cb) {
        v8s b = *(const v8s*)&Bs[cb * 16 + l15][h * 32 + quad * 8];
        acc[cb] = __builtin_amdgcn_mfma_f32_16x16x32_bf16(a, b, acc[cb], 0, 0, 0);
      }
    }
    __syncthreads();
  }
  bool f32o = (*outflag) != 0;
#pragma unroll
  for (int cb = 0; cb < 4; ++cb) {
    int col = j0 + cb * 16 + l15;
    float bv = bf2f(bias[col]);
#pragma unroll
    for (int r = 0; r < 4; ++r) {
      int row = i0 + w * 16 + quad * 4 + r;
      float v = acc[cb][r] + bv;
      size_t idx = (size_t)row * NB + col;
      if (f32o) ((float*)C)[idx] = v;
      else      ((u16*)C)[idx] = f2bf(v);
    }
  }
}

// ---------- fused attention (S^T scheme), split over keys ----------
// qb pre-scaled by QSCALE; adjE = exp2(ADJ2*adj). Block = (64 q-rows, head, split).
__global__ __launch_bounds__(256, 5) void attn_kernel(const u16* __restrict__ qb, const u16* __restrict__ kb,
                                                      const u16* __restrict__ vtb, const u16* __restrict__ adjE,
                                                      u16* __restrict__ Opart, float* __restrict__ Lpart) {
  __shared__ __align__(16) u16 Ks[64][72];
  __shared__ __align__(16) u16 Vs[64][72];      // Vs[e][m]
  __shared__ __align__(16) u16 Ps[4][16][72];   // per-wave private P[i][m]
  const int i0 = blockIdx.x * 64, h64 = blockIdx.y * 64, z = blockIdx.z;
  const int t = threadIdx.x, w = t >> 6, l = t & 63, quad = l >> 4, l15 = l & 15;
  const int iRow = i0 + w * 16 + l15;          // this lane's q-row

  v8s qf[2];
#pragma unroll
  for (int h = 0; h < 2; ++h)
    qf[h] = *(const v8s*)(qb + (size_t)iRow * HD + h64 + h * 32 + quad * 8);

  const u16* adjRow = adjE + (size_t)iRow * N_TOK;
  v4f oacc[4] = {};
  float lsum = 0.f;

  const int m_begin = z * (N_TOK / NSPLIT);
  for (int m0 = m_begin; m0 < m_begin + N_TOK / NSPLIT; m0 += 64) {
    // prefetch this lane's adjE strip (row iRow, 4 chunks of 4) — hidden behind staging+MFMA
    uint2 av[4];
#pragma unroll
    for (int cb = 0; cb < 4; ++cb)
      av[cb] = *(const uint2*)(adjRow + m0 + cb * 16 + quad * 4);

#pragma unroll
    for (int rep = 0; rep < 2; ++rep) {
      int idx = (t + rep * 256) * 8;
      int r = idx >> 6, c = idx & 63;
      *(v8s*)&Ks[r][c] = *(const v8s*)(kb  + (size_t)(m0 + r) * HD + h64 + c);
      *(v8s*)&Vs[r][c] = *(const v8s*)(vtb + (size_t)(h64 + r) * N_TOK + m0 + c);
    }
    __syncthreads();

    // S^T = K @ q^T : lane owns q-row i=l15, keys m = m0+cb*16+quad*4+r
    v4f s[4] = {};
#pragma unroll
    for (int h = 0; h < 2; ++h) {
#pragma unroll
      for (int cb = 0; cb < 4; ++cb) {
        v8s kf = *(const v8s*)&Ks[cb * 16 + l15][h * 32 + quad * 8];
        s[cb] = __builtin_amdgcn_mfma_f32_16x16x32_bf16(kf, qf[h], s[cb], 0, 0, 0);
      }
    }

    // p = exp2(sig*log2e) * E   (s already carries log2e/8; consts cancel in normalization)
#pragma unroll
    for (int cb = 0; cb < 4; ++cb) {
      union { unsigned int u; float f; } e0, e1, e2, e3;
      e0.u = av[cb].x << 16; e1.u = av[cb].x & 0xFFFF0000u;
      e2.u = av[cb].y << 16; e3.u = av[cb].y & 0xFFFF0000u;
      float p0, p1, p2, p3;
      {
        float u0 = fast_exp2(-s[cb][0]); p0 = fast_exp2(__builtin_amdgcn_rcpf(1.f + u0) * SIG2P) * e0.f;
        float u1 = fast_exp2(-s[cb][1]); p1 = fast_exp2(__builtin_amdgcn_rcpf(1.f + u1) * SIG2P) * e1.f;
        float u2 = fast_exp2(-s[cb][2]); p2 = fast_exp2(__builtin_amdgcn_rcpf(1.f + u2) * SIG2P) * e2.f;
        float u3 = fast_exp2(-s[cb][3]); p3 = fast_exp2(__builtin_amdgcn_rcpf(1.f + u3) * SIG2P) * e3.f;
      }
      lsum += (p0 + p1) + (p2 + p3);
      *(uint2*)&Ps[w][l15][cb * 16 + quad * 4] = make_uint2(pk_bf16(p0, p1), pk_bf16(p2, p3));
    }
    asm volatile("s_waitcnt lgkmcnt(0)" ::: "memory");  // Ps is wave-private

    // O += P @ v
#pragma unroll
    for (int h = 0; h < 2; ++h) {
      v8s pa = *(const v8s*)&Ps[w][l15][h * 32 + quad * 8];
#pragma unroll
      for (int eb = 0; eb < 4; ++eb) {
        v8s vf = *(const v8s*)&Vs[eb * 16 + l15][h * 32 + quad * 8];
        oacc[eb] = __builtin_amdgcn_mfma_f32_16x16x32_bf16(pa, vf, oacc[eb], 0, 0, 0);
      }
    }
    __syncthreads();
  }

  lsum += __shfl_xor(lsum, 16);
  lsum += __shfl_xor(lsum, 32);
  if (l < 16)
    Lpart[((size_t)z * N_TOK + i0 + w * 16 + l) * NH + blockIdx.y] = lsum;
#pragma unroll
  for (int eb = 0; eb < 4; ++eb) {
#pragma unroll
    for (int r = 0; r < 4; ++r) {
      size_t row = (size_t)z * N_TOK + i0 + w * 16 + quad * 4 + r;
      Opart[row * HD + h64 + eb * 16 + l15] = f2bf(oacc[eb][r]);
    }
  }
}

// ---------- combine split partials: ab = (sum_s O_s) / (sum_s l_s) ----------
__global__ __launch_bounds__(256) void reduce_k(const u16* __restrict__ Opart, const float* __restrict__ Lpart,
                                                u16* __restrict__ ab) {
  int i = blockIdx.x * 256 + threadIdx.x;   // over N*HD/4
  int row = i >> 7;                          // HD/4 = 128
  int c4 = i & 127;
  int h = c4 >> 4;
  float lv = 0.f;
#pragma unroll
  for (int s = 0; s < NSPLIT; ++s) lv += Lpart[((size_t)s * N_TOK + row) * NH + h];
  float ax = 0.f, ay = 0.f, az = 0.f, aw = 0.f;
#pragma unroll
  for (int s = 0; s < NSPLIT; ++s) {
    short4 v = ((const short4*)Opart)[(size_t)s * (N_TOK * HD / 4) + i];
    ax += bf2f((u16)v.x); ay += bf2f((u16)v.y); az += bf2f((u16)v.z); aw += bf2f((u16)v.w);
  }
  float rl = __builtin_amdgcn_rcpf(lv);
  ((uint2*)ab)[i] = make_uint2(pk_bf16(ax * rl, ay * rl), pk_bf16(az * rl, aw * rl));
}

extern "C" void kernel_launch(void* const* d_in, const int* in_sizes, int n_in,
                              void* d_out, int out_size, void* d_ws, size_t ws_size,
                              hipStream_t stream) {
  (void)in_sizes; (void)n_in; (void)out_size; (void)ws_size;
  const void* Q   = d_in[0];
  const void* K   = d_in[1];
  const void* V   = d_in[2];
  const void* adj = d_in[3];
  const void* WQ  = d_in[4];
  const void* bQ  = d_in[5];
  const void* WK  = d_in[6];
  const void* bK  = d_in[7];
  const void* WV  = d_in[8];
  const void* bV  = d_in[9];
  const void* WO  = d_in[10];
  const void* bO  = d_in[11];

  char* p = (char*)d_ws;
  auto alloc = [&](size_t bytes) { char* r = p; p += (bytes + 255) & ~(size_t)255; return r; };
  const size_t SZ = (size_t)N_TOK * HD * 2;

  int* flag    = (int*)alloc(256);
  u16* adjE    = (u16*)alloc((size_t)N_TOK * N_TOK * 2);
  u16* qb      = (u16*)alloc(SZ);
  u16* kb      = (u16*)alloc(SZ);
  u16* vb      = (u16*)alloc(SZ);
  u16* vtb     = (u16*)alloc(SZ);
  u16* ab      = (u16*)alloc(SZ);
  u16* Opart   = (u16*)alloc((size_t)NSPLIT * SZ);
  float* Lpart = (float*)alloc((size_t)NSPLIT * N_TOK * NH * 4);
  u16* tQ      = (u16*)alloc((size_t)512 * 512 * 2);
  u16* tK      = (u16*)alloc((size_t)512 * 512 * 2);
  u16* tV      = (u16*)alloc((size_t)512 * 512 * 2);
  u16* tO      = (u16*)alloc((size_t)64 * 512 * 2);
  u16* bQc     = (u16*)alloc(512 * 2);
  u16* bKc     = (u16*)alloc(512 * 2);
  u16* bVc     = (u16*)alloc(512 * 2);
  u16* bOc     = (u16*)alloc(64 * 2);

  dim3 b256(256);
  detect_k<<<1, 64, 0, stream>>>((const u16*)Q, flag);

  conv_adjE_k<<<dim3(16384 + 7), b256, 0, stream>>>(adj, adjE, bQ, bK, bV, bO,
                                                    bQc, bKc, bVc, bOc, flag);
  tr_w_k<<<dim3(8, 8, 4), b256, 0, stream>>>(WQ, WK, WV, WO, tQ, tK, tV, tO, flag);

  gemm_qkv_k<<<dim3(64, 8, 3), b256, 0, stream>>>(Q, K, V, tQ, tK, tV,
                                                  bQc, bKc, bVc, qb, kb, vb, flag);

  tr_bf16<<<dim3(64, 8), b256, 0, stream>>>(vb, vtb, N_TOK, HD);

  attn_kernel<<<dim3(N_TOK / 64, NH, NSPLIT), b256, 0, stream>>>(qb, kb, vtb, adjE, Opart, Lpart);

  reduce_k<<<dim3(N_TOK * HD / 4 / 256), b256, 0, stream>>>(Opart, Lpart, ab);

  gemm_bt<<<dim3(64, 1), b256, 0, stream>>>(ab, tO, bOc, d_out, flag, 64, 512);
}